// Round 5
// baseline (627.160 us; speedup 1.0000x reference)
//
#include <hip/hip_runtime.h>
#include <hip/hip_bf16.h>
#include <cstdint>
#include <cstddef>

#define B_ 16384
#define F_ 4096
#define P_ 32
#define D_ 128
#define STRIPS 32      // strips per partition; grid = P_*STRIPS = 1024 blocks
#define ITERS 8        // per wave: 8 tiles of 16 rows (4 waves -> 512 rows/block)

using f32x4 = __attribute__((ext_vector_type(4))) float;
using s16x8 = __attribute__((ext_vector_type(8))) short;

union abuf { s16x8 v; uint32_t u[4]; };

__device__ inline uint32_t pk_bf16(float a, float b) {
    float2 f; f.x = a; f.y = b;
    union { __hip_bfloat162 h; uint32_t u; } cv;
    cv.h = __float22bfloat162_rn(f);
    return cv.u;
}
// tanh(z) = 1 - 2/(e^{2z}+1); caller passes ze = 2*log2(e)*z (folded into BN)
__device__ inline float tanh_e(float ze) {
    float e = __builtin_amdgcn_exp2f(ze);
    return 1.f - 2.f * __builtin_amdgcn_rcpf(e + 1.f);
}

// Stage W[p] (128x128 f32, row-major [k][c]) into LDS as MFMA A-operand
// fragments with k-permutation k(sp,l4,t) = sp*32 + (t>=4)*16 + l4*4 + (t&3).
// This permutation matches a B-operand built from f32x4 loads at cols
// j*16 + l4*4 (pairs j=2sp, 2sp+1), so the x tile doubles as the residual.
// Wave read for (j,sp) = contiguous 1KB (lane*16) -> conflict-free b128.
__device__ inline void stage_wp(const float* __restrict__ Wp, short* s_w, int tid) {
#pragma unroll
    for (int it = 0; it < 8; ++it) {
        int slot = it * 256 + tid;
        int l15 = slot & 15;
        int l4  = (slot >> 4) & 3;
        int sp  = (slot >> 6) & 3;
        int j   = slot >> 8;
        const float* s0 = Wp + (size_t)(sp * 32 + l4 * 4) * D_ + j * 16 + l15;
        const float* s1 = s0 + (size_t)16 * D_;
        abuf a;
        a.u[0] = pk_bf16(s0[0],            s0[(size_t)D_]);
        a.u[1] = pk_bf16(s0[(size_t)2*D_], s0[(size_t)3*D_]);
        a.u[2] = pk_bf16(s1[0],            s1[(size_t)D_]);
        a.u[3] = pk_bf16(s1[(size_t)2*D_], s1[(size_t)3*D_]);
        *(s16x8*)((char*)s_w + (size_t)slot * 16) = a.v;
    }
}

// ---- K1: stats of y1 = x @ BD(W1); y1 lives only in registers -------------
__global__ __launch_bounds__(256, 3) void k_stats1(
    const float* __restrict__ x, const float* __restrict__ W1,
    float* __restrict__ gsum, float* __restrict__ gsq)
{
    __shared__ short s_w[D_ * D_];
    __shared__ float s_sum[D_], s_sq[D_];
    const int tid = threadIdx.x;
    const int p = blockIdx.x / STRIPS, strip = blockIdx.x % STRIPS;
    stage_wp(W1 + (size_t)p * D_ * D_, s_w, tid);
    if (tid < D_) { s_sum[tid] = 0.f; s_sq[tid] = 0.f; }
    __syncthreads();
    const int wave = tid >> 6, lane = tid & 63;
    const int l15 = lane & 15, l4 = lane >> 4;
    const int ldsb = lane * 16;

    f32x4 csum[8], csq[8];
#pragma unroll
    for (int j = 0; j < 8; ++j) { csum[j] = (f32x4){0,0,0,0}; csq[j] = (f32x4){0,0,0,0}; }

    for (int it = 0; it < ITERS; ++it) {
        const int g = strip * 32 + it * 4 + wave;
        const float* ap = x + (size_t)(g * 16 + l15) * F_ + p * D_ + l4 * 4;
        f32x4 xv[8];
#pragma unroll
        for (int j = 0; j < 8; ++j)
            xv[j] = __builtin_nontemporal_load((const f32x4*)(ap + j * 16));
        abuf a[4];
#pragma unroll
        for (int s = 0; s < 4; ++s) {
            a[s].u[0] = pk_bf16(xv[2*s][0],   xv[2*s][1]);
            a[s].u[1] = pk_bf16(xv[2*s][2],   xv[2*s][3]);
            a[s].u[2] = pk_bf16(xv[2*s+1][0], xv[2*s+1][1]);
            a[s].u[3] = pk_bf16(xv[2*s+1][2], xv[2*s+1][3]);
        }
        f32x4 acc[8];
#pragma unroll
        for (int j = 0; j < 8; ++j) acc[j] = (f32x4){0,0,0,0};
#pragma unroll
        for (int s = 0; s < 4; ++s)
#pragma unroll
            for (int j = 0; j < 8; ++j) {
                s16x8 w = *(const s16x8*)((const char*)s_w + (j * 4 + s) * 1024 + ldsb);
                acc[j] = __builtin_amdgcn_mfma_f32_16x16x32_bf16(w, a[s].v, acc[j], 0, 0, 0);
            }
#pragma unroll
        for (int j = 0; j < 8; ++j)
#pragma unroll
            for (int r = 0; r < 4; ++r) {
                float v = acc[j][r];
                csum[j][r] += v;
                csq[j][r] = fmaf(v, v, csq[j][r]);
            }
    }
#pragma unroll
    for (int j = 0; j < 8; ++j)
#pragma unroll
        for (int r = 0; r < 4; ++r) {
            float sm = csum[j][r], q = csq[j][r];
            sm += __shfl_xor(sm, 1); q += __shfl_xor(q, 1);
            sm += __shfl_xor(sm, 2); q += __shfl_xor(q, 2);
            sm += __shfl_xor(sm, 4); q += __shfl_xor(q, 4);
            sm += __shfl_xor(sm, 8); q += __shfl_xor(q, 8);
            if (l15 == 0) {
                atomicAdd(&s_sum[j * 16 + l4 * 4 + r], sm);
                atomicAdd(&s_sq [j * 16 + l4 * 4 + r], q);
            }
        }
    __syncthreads();
    if (tid < D_) {
        atomicAdd(&gsum[p * D_ + tid], s_sum[tid]);
        atomicAdd(&gsq [p * D_ + tid], s_sq[tid]);
    }
}

// ---- K2: y3 = tanh(bn1(x@W1)) @ BD(W2) + x, one x read, fused stats3 ------
__global__ __launch_bounds__(256, 2) void k_fused(
    const float* __restrict__ x, float* __restrict__ yf,
    const float* __restrict__ W1, const float* __restrict__ W2,
    const float* __restrict__ sce, const float* __restrict__ she,
    float* __restrict__ gsum, float* __restrict__ gsq)
{
    __shared__ short s_w1[D_ * D_];
    __shared__ short s_w2[D_ * D_];
    __shared__ float s_sc[D_], s_sh[D_];
    __shared__ float s_sum[D_], s_sq[D_];
    const int tid = threadIdx.x;
    const int p = blockIdx.x / STRIPS, strip = blockIdx.x % STRIPS;
    stage_wp(W1 + (size_t)p * D_ * D_, s_w1, tid);
    stage_wp(W2 + (size_t)p * D_ * D_, s_w2, tid);
    if (tid < D_) {
        s_sc[tid] = sce[p * D_ + tid];
        s_sh[tid] = she[p * D_ + tid];
        s_sum[tid] = 0.f; s_sq[tid] = 0.f;
    }
    __syncthreads();
    const int wave = tid >> 6, lane = tid & 63;
    const int l15 = lane & 15, l4 = lane >> 4;
    const int ldsb = lane * 16;

    f32x4 csum[8], csq[8];
#pragma unroll
    for (int j = 0; j < 8; ++j) { csum[j] = (f32x4){0,0,0,0}; csq[j] = (f32x4){0,0,0,0}; }

    auto LOADX = [&](f32x4 (&xv)[8], int it) {
        const int g = strip * 32 + it * 4 + wave;
        const float* ap = x + (size_t)(g * 16 + l15) * F_ + p * D_ + l4 * 4;
#pragma unroll
        for (int j = 0; j < 8; ++j)
            xv[j] = __builtin_nontemporal_load((const f32x4*)(ap + j * 16));
    };

    auto TILE = [&](f32x4 (&xv)[8], int it) {
        // ---- GEMM1 recompute ----
        abuf a[4];
#pragma unroll
        for (int s = 0; s < 4; ++s) {
            a[s].u[0] = pk_bf16(xv[2*s][0],   xv[2*s][1]);
            a[s].u[1] = pk_bf16(xv[2*s][2],   xv[2*s][3]);
            a[s].u[2] = pk_bf16(xv[2*s+1][0], xv[2*s+1][1]);
            a[s].u[3] = pk_bf16(xv[2*s+1][2], xv[2*s+1][3]);
        }
        f32x4 acc[8];
#pragma unroll
        for (int j = 0; j < 8; ++j) acc[j] = (f32x4){0,0,0,0};
#pragma unroll
        for (int s = 0; s < 4; ++s)
#pragma unroll
            for (int j = 0; j < 8; ++j) {
                s16x8 w = *(const s16x8*)((const char*)s_w1 + (j * 4 + s) * 1024 + ldsb);
                acc[j] = __builtin_amdgcn_mfma_f32_16x16x32_bf16(w, a[s].v, acc[j], 0, 0, 0);
            }
        // ---- bn1 + tanh -> B-fragments for GEMM2 ----
#pragma unroll
        for (int sp = 0; sp < 4; ++sp) {
            const int kb = sp * 32 + l4 * 4;
            f32x4 sc0 = *(const f32x4*)&s_sc[kb], sc1 = *(const f32x4*)&s_sc[kb + 16];
            f32x4 sh0 = *(const f32x4*)&s_sh[kb], sh1 = *(const f32x4*)&s_sh[kb + 16];
            float t0[4], t1[4];
#pragma unroll
            for (int q = 0; q < 4; ++q) {
                t0[q] = tanh_e(fmaf(acc[2*sp][q],   sc0[q], sh0[q]));
                t1[q] = tanh_e(fmaf(acc[2*sp+1][q], sc1[q], sh1[q]));
            }
            a[sp].u[0] = pk_bf16(t0[0], t0[1]);
            a[sp].u[1] = pk_bf16(t0[2], t0[3]);
            a[sp].u[2] = pk_bf16(t1[0], t1[1]);
            a[sp].u[3] = pk_bf16(t1[2], t1[3]);
        }
        // ---- GEMM2 ----
#pragma unroll
        for (int j = 0; j < 8; ++j) acc[j] = (f32x4){0,0,0,0};
#pragma unroll
        for (int sp = 0; sp < 4; ++sp)
#pragma unroll
            for (int j = 0; j < 8; ++j) {
                s16x8 w = *(const s16x8*)((const char*)s_w2 + (j * 4 + sp) * 1024 + ldsb);
                acc[j] = __builtin_amdgcn_mfma_f32_16x16x32_bf16(w, a[sp].v, acc[j], 0, 0, 0);
            }
        // ---- residual from the SAME registers, store, stats ----
        const int g = strip * 32 + it * 4 + wave;
        float* rp = yf + (size_t)(g * 16 + l15) * F_ + p * D_ + l4 * 4;
#pragma unroll
        for (int j = 0; j < 8; ++j) {
            f32x4 o;
#pragma unroll
            for (int r = 0; r < 4; ++r) {
                float v = acc[j][r] + xv[j][r];
                o[r] = v;
                csum[j][r] += v;
                csq[j][r] = fmaf(v, v, csq[j][r]);
            }
            __builtin_nontemporal_store(o, (f32x4*)(rp + j * 16));
        }
    };

    f32x4 xv0[8], xv1[8];
    LOADX(xv0, 0);
#pragma unroll
    for (int h = 0; h < 4; ++h) {
        LOADX(xv1, 2 * h + 1);
        TILE(xv0, 2 * h);
        if (h < 3) LOADX(xv0, 2 * h + 2);
        TILE(xv1, 2 * h + 1);
    }

#pragma unroll
    for (int j = 0; j < 8; ++j)
#pragma unroll
        for (int r = 0; r < 4; ++r) {
            float sm = csum[j][r], q = csq[j][r];
            sm += __shfl_xor(sm, 1); q += __shfl_xor(q, 1);
            sm += __shfl_xor(sm, 2); q += __shfl_xor(q, 2);
            sm += __shfl_xor(sm, 4); q += __shfl_xor(q, 4);
            sm += __shfl_xor(sm, 8); q += __shfl_xor(q, 8);
            if (l15 == 0) {
                atomicAdd(&s_sum[j * 16 + l4 * 4 + r], sm);
                atomicAdd(&s_sq [j * 16 + l4 * 4 + r], q);
            }
        }
    __syncthreads();
    if (tid < D_) {
        atomicAdd(&gsum[p * D_ + tid], s_sum[tid]);
        atomicAdd(&gsq [p * D_ + tid], s_sq[tid]);
    }
}

// --- BN finalize: scale/shift pre-multiplied by 2*log2(e) for tanh_e -------
__global__ void k_finalize(const float* __restrict__ sum,
                           const float* __restrict__ sumsq,
                           const float* __restrict__ gamma,
                           const float* __restrict__ beta,
                           float* __restrict__ sce, float* __restrict__ she)
{
    const float L2E2 = 2.f * 1.44269504088896340736f;
    int f = blockIdx.x * blockDim.x + threadIdx.x;
    if (f < F_) {
        float mean = sum[f] * (1.f / B_);
        float var  = sumsq[f] * (1.f / B_) - mean * mean;
        float rstd = rsqrtf(var + 1e-5f);
        float sc = gamma[f] * rstd;
        sce[f] = L2E2 * sc;
        she[f] = L2E2 * (beta[f] - mean * sc);
    }
}

// ----------- final elementwise: o3 = tanh(bn3(y3)), in place on d_out ------
__global__ void k_bn_tanh(float* yb, const float* __restrict__ sce,
                          const float* __restrict__ she)
{
    const size_t n4 = (size_t)B_ * F_ / 4;
    size_t i = (size_t)blockIdx.x * blockDim.x + threadIdx.x;
    const size_t stride = (size_t)gridDim.x * blockDim.x;
    for (; i < n4; i += stride) {
        f32x4 v = __builtin_nontemporal_load((const f32x4*)yb + i);
        int col = (int)((i * 4) & (F_ - 1));
        f32x4 sc = *(const f32x4*)(sce + col);
        f32x4 sh = *(const f32x4*)(she + col);
        f32x4 r;
#pragma unroll
        for (int t = 0; t < 4; ++t) r[t] = tanh_e(fmaf(v[t], sc[t], sh[t]));
        __builtin_nontemporal_store(r, (f32x4*)yb + i);
    }
}

extern "C" void kernel_launch(void* const* d_in, const int* in_sizes, int n_in,
                              void* d_out, int out_size, void* d_ws, size_t ws_size,
                              hipStream_t stream) {
    const float* x      = (const float*)d_in[0];
    const float* W1     = (const float*)d_in[1];
    // d_in[2] = bias1 (cancels inside BN1)
    const float* W2     = (const float*)d_in[3];
    // d_in[4] = bias2 (cancels inside BN3)
    const float* gamma1 = (const float*)d_in[5];
    const float* beta1  = (const float*)d_in[6];
    const float* gamma3 = (const float*)d_in[7];
    const float* beta3  = (const float*)d_in[8];

    float* yf = (float*)d_out;
    float* S  = (float*)d_ws;                  // 128KB stats block
    float* sum1 = S;                           // zeroed
    float* sq1  = S + 4096;                    // zeroed
    float* sum3 = S + 8192;                    // zeroed
    float* sq3  = S + 12288;                   // zeroed
    float* sce1 = S + 16384;
    float* she1 = S + 20480;
    float* sce3 = S + 24576;
    float* she3 = S + 28672;

    hipMemsetAsync(d_ws, 0, 4 * 4096 * sizeof(float), stream);

    k_stats1<<<P_ * STRIPS, 256, 0, stream>>>(x, W1, sum1, sq1);
    k_finalize<<<F_ / 256, 256, 0, stream>>>(sum1, sq1, gamma1, beta1, sce1, she1);
    k_fused<<<P_ * STRIPS, 256, 0, stream>>>(x, yf, W1, W2, sce1, she1, sum3, sq3);
    k_finalize<<<F_ / 256, 256, 0, stream>>>(sum3, sq3, gamma3, beta3, sce3, she3);
    k_bn_tanh<<<4096, 256, 0, stream>>>(yf, sce3, she3);
}

// Round 6
// 624.841 us; speedup vs baseline: 1.0037x; 1.0037x over previous
//
#include <hip/hip_runtime.h>
#include <hip/hip_bf16.h>
#include <cstdint>
#include <cstddef>

#define B_ 16384
#define F_ 4096
#define P_ 32
#define D_ 128
#define STRIPS 32      // strips per partition; grid = P_*STRIPS = 1024 blocks
#define ITERS 8        // per wave: 8 tiles of 16 rows (4 waves -> 512 rows/block)

using f32x4 = __attribute__((ext_vector_type(4))) float;
using s16x8 = __attribute__((ext_vector_type(8))) short;

union abuf { s16x8 v; uint32_t u[4]; };

__device__ inline uint32_t pk_bf16(float a, float b) {
    float2 f; f.x = a; f.y = b;
    union { __hip_bfloat162 h; uint32_t u; } cv;
    cv.h = __float22bfloat162_rn(f);
    return cv.u;
}
// tanh(z) = 1 - 2/(e^{2z}+1); caller passes ze = 2*log2(e)*z (folded into BN)
__device__ inline float tanh_e(float ze) {
    float e = __builtin_amdgcn_exp2f(ze);
    return 1.f - 2.f * __builtin_amdgcn_rcpf(e + 1.f);
}

// Stage W[p] (128x128 f32, row-major [k][c]) into LDS as MFMA A-operand
// fragments with k-permutation k(sp,l4,t) = sp*32 + (t>=4)*16 + l4*4 + (t&3).
// This permutation matches a B-operand built from f32x4 loads at cols
// j*16 + l4*4 (pairs j=2sp, 2sp+1), so the x tile doubles as the residual.
// Wave read for (j,sp) = contiguous 1KB (lane*16) -> conflict-free b128.
__device__ inline void stage_wp(const float* __restrict__ Wp, short* s_w, int tid) {
#pragma unroll
    for (int it = 0; it < 8; ++it) {
        int slot = it * 256 + tid;
        int l15 = slot & 15;
        int l4  = (slot >> 4) & 3;
        int sp  = (slot >> 6) & 3;
        int j   = slot >> 8;
        const float* s0 = Wp + (size_t)(sp * 32 + l4 * 4) * D_ + j * 16 + l15;
        const float* s1 = s0 + (size_t)16 * D_;
        abuf a;
        a.u[0] = pk_bf16(s0[0],            s0[(size_t)D_]);
        a.u[1] = pk_bf16(s0[(size_t)2*D_], s0[(size_t)3*D_]);
        a.u[2] = pk_bf16(s1[0],            s1[(size_t)D_]);
        a.u[3] = pk_bf16(s1[(size_t)2*D_], s1[(size_t)3*D_]);
        *(s16x8*)((char*)s_w + (size_t)slot * 16) = a.v;
    }
}

// ---- K1: stats of y1 = x @ BD(W1); y1 lives only in registers -------------
__global__ __launch_bounds__(256, 3) void k_stats1(
    const float* __restrict__ x, const float* __restrict__ W1,
    float* __restrict__ gsum, float* __restrict__ gsq)
{
    __shared__ short s_w[D_ * D_];
    __shared__ float s_sum[D_], s_sq[D_];
    const int tid = threadIdx.x;
    const int p = blockIdx.x / STRIPS, strip = blockIdx.x % STRIPS;
    stage_wp(W1 + (size_t)p * D_ * D_, s_w, tid);
    if (tid < D_) { s_sum[tid] = 0.f; s_sq[tid] = 0.f; }
    __syncthreads();
    const int wave = tid >> 6, lane = tid & 63;
    const int l15 = lane & 15, l4 = lane >> 4;
    const int ldsb = lane * 16;

    f32x4 csum[8], csq[8];
#pragma unroll
    for (int j = 0; j < 8; ++j) { csum[j] = (f32x4){0,0,0,0}; csq[j] = (f32x4){0,0,0,0}; }

    f32x4 xv[8];
    {
        const float* ap = x + (size_t)((strip * 32 + wave) * 16 + l15) * F_ + p * D_ + l4 * 4;
#pragma unroll
        for (int j = 0; j < 8; ++j) xv[j] = *(const f32x4*)(ap + j * 16);
    }
#pragma unroll
    for (int it = 0; it < ITERS; ++it) {
        // build bf16 fragments (xv dies here)
        abuf a[4];
#pragma unroll
        for (int s = 0; s < 4; ++s) {
            a[s].u[0] = pk_bf16(xv[2*s][0],   xv[2*s][1]);
            a[s].u[1] = pk_bf16(xv[2*s][2],   xv[2*s][3]);
            a[s].u[2] = pk_bf16(xv[2*s+1][0], xv[2*s+1][1]);
            a[s].u[3] = pk_bf16(xv[2*s+1][2], xv[2*s+1][3]);
        }
        // issue next tile's loads; they fly under the MFMAs below
        if (it + 1 < ITERS) {
            const int g = strip * 32 + (it + 1) * 4 + wave;
            const float* ap = x + (size_t)(g * 16 + l15) * F_ + p * D_ + l4 * 4;
#pragma unroll
            for (int j = 0; j < 8; ++j) xv[j] = *(const f32x4*)(ap + j * 16);
        }
        f32x4 acc[8];
#pragma unroll
        for (int j = 0; j < 8; ++j) acc[j] = (f32x4){0,0,0,0};
#pragma unroll
        for (int s = 0; s < 4; ++s)
#pragma unroll
            for (int j = 0; j < 8; ++j) {
                s16x8 w = *(const s16x8*)((const char*)s_w + (j * 4 + s) * 1024 + ldsb);
                acc[j] = __builtin_amdgcn_mfma_f32_16x16x32_bf16(w, a[s].v, acc[j], 0, 0, 0);
            }
#pragma unroll
        for (int j = 0; j < 8; ++j)
#pragma unroll
            for (int r = 0; r < 4; ++r) {
                float v = acc[j][r];
                csum[j][r] += v;
                csq[j][r] = fmaf(v, v, csq[j][r]);
            }
    }
#pragma unroll
    for (int j = 0; j < 8; ++j)
#pragma unroll
        for (int r = 0; r < 4; ++r) {
            float sm = csum[j][r], q = csq[j][r];
            sm += __shfl_xor(sm, 1); q += __shfl_xor(q, 1);
            sm += __shfl_xor(sm, 2); q += __shfl_xor(q, 2);
            sm += __shfl_xor(sm, 4); q += __shfl_xor(q, 4);
            sm += __shfl_xor(sm, 8); q += __shfl_xor(q, 8);
            if (l15 == 0) {
                atomicAdd(&s_sum[j * 16 + l4 * 4 + r], sm);
                atomicAdd(&s_sq [j * 16 + l4 * 4 + r], q);
            }
        }
    __syncthreads();
    if (tid < D_) {
        atomicAdd(&gsum[p * D_ + tid], s_sum[tid]);
        atomicAdd(&gsq [p * D_ + tid], s_sq[tid]);
    }
}

// ---- K2: y3 = tanh(bn1(x@W1)) @ BD(W2) + x, one x read, fused stats3 ------
__global__ __launch_bounds__(256, 2) void k_fused(
    const float* __restrict__ x, float* __restrict__ yf,
    const float* __restrict__ W1, const float* __restrict__ W2,
    const float* __restrict__ sce, const float* __restrict__ she,
    float* __restrict__ gsum, float* __restrict__ gsq)
{
    __shared__ short s_w1[D_ * D_];
    __shared__ short s_w2[D_ * D_];
    __shared__ float s_sc[D_], s_sh[D_];
    __shared__ float s_sum[D_], s_sq[D_];
    const int tid = threadIdx.x;
    const int p = blockIdx.x / STRIPS, strip = blockIdx.x % STRIPS;
    stage_wp(W1 + (size_t)p * D_ * D_, s_w1, tid);
    stage_wp(W2 + (size_t)p * D_ * D_, s_w2, tid);
    if (tid < D_) {
        s_sc[tid] = sce[p * D_ + tid];
        s_sh[tid] = she[p * D_ + tid];
        s_sum[tid] = 0.f; s_sq[tid] = 0.f;
    }
    __syncthreads();
    const int wave = tid >> 6, lane = tid & 63;
    const int l15 = lane & 15, l4 = lane >> 4;
    const int ldsb = lane * 16;

    f32x4 csum[8], csq[8];
#pragma unroll
    for (int j = 0; j < 8; ++j) { csum[j] = (f32x4){0,0,0,0}; csq[j] = (f32x4){0,0,0,0}; }

    auto LOADX = [&](f32x4 (&xv)[8], int it) {
        const int g = strip * 32 + it * 4 + wave;
        const float* ap = x + (size_t)(g * 16 + l15) * F_ + p * D_ + l4 * 4;
#pragma unroll
        for (int j = 0; j < 8; ++j)
            xv[j] = *(const f32x4*)(ap + j * 16);
    };

    auto TILE = [&](f32x4 (&xv)[8], int it) {
        // ---- GEMM1 recompute ----
        abuf a[4];
#pragma unroll
        for (int s = 0; s < 4; ++s) {
            a[s].u[0] = pk_bf16(xv[2*s][0],   xv[2*s][1]);
            a[s].u[1] = pk_bf16(xv[2*s][2],   xv[2*s][3]);
            a[s].u[2] = pk_bf16(xv[2*s+1][0], xv[2*s+1][1]);
            a[s].u[3] = pk_bf16(xv[2*s+1][2], xv[2*s+1][3]);
        }
        f32x4 acc[8];
#pragma unroll
        for (int j = 0; j < 8; ++j) acc[j] = (f32x4){0,0,0,0};
#pragma unroll
        for (int s = 0; s < 4; ++s)
#pragma unroll
            for (int j = 0; j < 8; ++j) {
                s16x8 w = *(const s16x8*)((const char*)s_w1 + (j * 4 + s) * 1024 + ldsb);
                acc[j] = __builtin_amdgcn_mfma_f32_16x16x32_bf16(w, a[s].v, acc[j], 0, 0, 0);
            }
        // ---- bn1 + tanh -> B-fragments for GEMM2 ----
#pragma unroll
        for (int sp = 0; sp < 4; ++sp) {
            const int kb = sp * 32 + l4 * 4;
            f32x4 sc0 = *(const f32x4*)&s_sc[kb], sc1 = *(const f32x4*)&s_sc[kb + 16];
            f32x4 sh0 = *(const f32x4*)&s_sh[kb], sh1 = *(const f32x4*)&s_sh[kb + 16];
            float t0[4], t1[4];
#pragma unroll
            for (int q = 0; q < 4; ++q) {
                t0[q] = tanh_e(fmaf(acc[2*sp][q],   sc0[q], sh0[q]));
                t1[q] = tanh_e(fmaf(acc[2*sp+1][q], sc1[q], sh1[q]));
            }
            a[sp].u[0] = pk_bf16(t0[0], t0[1]);
            a[sp].u[1] = pk_bf16(t0[2], t0[3]);
            a[sp].u[2] = pk_bf16(t1[0], t1[1]);
            a[sp].u[3] = pk_bf16(t1[2], t1[3]);
        }
        // ---- GEMM2 ----
#pragma unroll
        for (int j = 0; j < 8; ++j) acc[j] = (f32x4){0,0,0,0};
#pragma unroll
        for (int sp = 0; sp < 4; ++sp)
#pragma unroll
            for (int j = 0; j < 8; ++j) {
                s16x8 w = *(const s16x8*)((const char*)s_w2 + (j * 4 + sp) * 1024 + ldsb);
                acc[j] = __builtin_amdgcn_mfma_f32_16x16x32_bf16(w, a[sp].v, acc[j], 0, 0, 0);
            }
        // ---- residual from the SAME registers, store, stats ----
        const int g = strip * 32 + it * 4 + wave;
        float* rp = yf + (size_t)(g * 16 + l15) * F_ + p * D_ + l4 * 4;
#pragma unroll
        for (int j = 0; j < 8; ++j) {
            f32x4 o;
#pragma unroll
            for (int r = 0; r < 4; ++r) {
                float v = acc[j][r] + xv[j][r];
                o[r] = v;
                csum[j][r] += v;
                csq[j][r] = fmaf(v, v, csq[j][r]);
            }
            __builtin_nontemporal_store(o, (f32x4*)(rp + j * 16));
        }
    };

    f32x4 xv0[8], xv1[8];
    LOADX(xv0, 0);
#pragma unroll
    for (int h = 0; h < 4; ++h) {
        LOADX(xv1, 2 * h + 1);
        TILE(xv0, 2 * h);
        if (h < 3) LOADX(xv0, 2 * h + 2);
        TILE(xv1, 2 * h + 1);
    }

#pragma unroll
    for (int j = 0; j < 8; ++j)
#pragma unroll
        for (int r = 0; r < 4; ++r) {
            float sm = csum[j][r], q = csq[j][r];
            sm += __shfl_xor(sm, 1); q += __shfl_xor(q, 1);
            sm += __shfl_xor(sm, 2); q += __shfl_xor(q, 2);
            sm += __shfl_xor(sm, 4); q += __shfl_xor(q, 4);
            sm += __shfl_xor(sm, 8); q += __shfl_xor(q, 8);
            if (l15 == 0) {
                atomicAdd(&s_sum[j * 16 + l4 * 4 + r], sm);
                atomicAdd(&s_sq [j * 16 + l4 * 4 + r], q);
            }
        }
    __syncthreads();
    if (tid < D_) {
        atomicAdd(&gsum[p * D_ + tid], s_sum[tid]);
        atomicAdd(&gsq [p * D_ + tid], s_sq[tid]);
    }
}

// --- BN finalize: scale/shift pre-multiplied by 2*log2(e) for tanh_e -------
__global__ void k_finalize(const float* __restrict__ sum,
                           const float* __restrict__ sumsq,
                           const float* __restrict__ gamma,
                           const float* __restrict__ beta,
                           float* __restrict__ sce, float* __restrict__ she)
{
    const float L2E2 = 2.f * 1.44269504088896340736f;
    int f = blockIdx.x * blockDim.x + threadIdx.x;
    if (f < F_) {
        float mean = sum[f] * (1.f / B_);
        float var  = sumsq[f] * (1.f / B_) - mean * mean;
        float rstd = rsqrtf(var + 1e-5f);
        float sc = gamma[f] * rstd;
        sce[f] = L2E2 * sc;
        she[f] = L2E2 * (beta[f] - mean * sc);
    }
}

// ----------- final elementwise: o3 = tanh(bn3(y3)), in place on d_out ------
__global__ void k_bn_tanh(float* yb, const float* __restrict__ sce,
                          const float* __restrict__ she)
{
    const size_t n4 = (size_t)B_ * F_ / 4;
    size_t i = (size_t)blockIdx.x * blockDim.x + threadIdx.x;
    const size_t stride = (size_t)gridDim.x * blockDim.x;
    for (; i < n4; i += stride) {
        f32x4 v = ((const f32x4*)yb)[i];
        int col = (int)((i * 4) & (F_ - 1));
        f32x4 sc = *(const f32x4*)(sce + col);
        f32x4 sh = *(const f32x4*)(she + col);
        f32x4 r;
#pragma unroll
        for (int t = 0; t < 4; ++t) r[t] = tanh_e(fmaf(v[t], sc[t], sh[t]));
        __builtin_nontemporal_store(r, (f32x4*)yb + i);
    }
}

extern "C" void kernel_launch(void* const* d_in, const int* in_sizes, int n_in,
                              void* d_out, int out_size, void* d_ws, size_t ws_size,
                              hipStream_t stream) {
    const float* x      = (const float*)d_in[0];
    const float* W1     = (const float*)d_in[1];
    // d_in[2] = bias1 (cancels inside BN1)
    const float* W2     = (const float*)d_in[3];
    // d_in[4] = bias2 (cancels inside BN3)
    const float* gamma1 = (const float*)d_in[5];
    const float* beta1  = (const float*)d_in[6];
    const float* gamma3 = (const float*)d_in[7];
    const float* beta3  = (const float*)d_in[8];

    float* yf = (float*)d_out;
    float* S  = (float*)d_ws;                  // 128KB stats block
    float* sum1 = S;                           // zeroed
    float* sq1  = S + 4096;                    // zeroed
    float* sum3 = S + 8192;                    // zeroed
    float* sq3  = S + 12288;                   // zeroed
    float* sce1 = S + 16384;
    float* she1 = S + 20480;
    float* sce3 = S + 24576;
    float* she3 = S + 28672;

    hipMemsetAsync(d_ws, 0, 4 * 4096 * sizeof(float), stream);

    k_stats1<<<P_ * STRIPS, 256, 0, stream>>>(x, W1, sum1, sq1);
    k_finalize<<<F_ / 256, 256, 0, stream>>>(sum1, sq1, gamma1, beta1, sce1, she1);
    k_fused<<<P_ * STRIPS, 256, 0, stream>>>(x, yf, W1, W2, sce1, she1, sum3, sq3);
    k_finalize<<<F_ / 256, 256, 0, stream>>>(sum3, sq3, gamma3, beta3, sce3, she3);
    k_bn_tanh<<<4096, 256, 0, stream>>>(yf, sce3, she3);
}

// Round 7
// 559.815 us; speedup vs baseline: 1.1203x; 1.1162x over previous
//
#include <hip/hip_runtime.h>
#include <hip/hip_bf16.h>
#include <hip/hip_fp16.h>
#include <cstdint>
#include <cstddef>

#define B_ 16384
#define F_ 4096
#define P_ 32
#define D_ 128
#define STRIPS 32      // strips per partition; grid = P_*STRIPS = 1024 blocks
#define ITERS 8        // per wave: 8 tiles of 16 rows (4 waves -> 512 rows/block)

using f32x4 = __attribute__((ext_vector_type(4))) float;
using s16x8 = __attribute__((ext_vector_type(8))) short;

union abuf { s16x8 v; uint32_t u[4]; };

__device__ inline uint32_t pk_bf16(float a, float b) {
    float2 f; f.x = a; f.y = b;
    union { __hip_bfloat162 h; uint32_t u; } cv;
    cv.h = __float22bfloat162_rn(f);
    return cv.u;
}
__device__ inline uint32_t pk_f16(float a, float b) {
    float2 f; f.x = a; f.y = b;
    union { __half2 h; uint32_t u; } cv;
    cv.h = __float22half2_rn(f);
    return cv.u;
}
__device__ inline float f16_f32(unsigned short h) {
    union { unsigned short u; __half h; } cv; cv.u = h;
    return __half2float(cv.h);
}
// tanh(z) = 1 - 2/(e^{2z}+1); caller passes ze = 2*log2(e)*z (folded into BN)
__device__ inline float tanh_e(float ze) {
    float e = __builtin_amdgcn_exp2f(ze);
    return 1.f - 2.f * __builtin_amdgcn_rcpf(e + 1.f);
}

// Stage W[p] (128x128 f32, row-major [k][c]) into LDS as MFMA A-operand
// fragments with k-permutation k(sp,l4,t) = sp*32 + (t>=4)*16 + l4*4 + (t&3).
// Matches a B-operand built from f32x4 loads at cols j*16 + l4*4, so the
// loaded x tile doubles as the residual. Wave read for (j,sp) = contiguous
// 1KB (lane*16) -> conflict-free ds_read_b128 (verified: 0 conflicts).
__device__ inline void stage_wp(const float* __restrict__ Wp, short* s_w, int tid) {
#pragma unroll
    for (int it = 0; it < 8; ++it) {
        int slot = it * 256 + tid;
        int l15 = slot & 15;
        int l4  = (slot >> 4) & 3;
        int sp  = (slot >> 6) & 3;
        int j   = slot >> 8;
        const float* s0 = Wp + (size_t)(sp * 32 + l4 * 4) * D_ + j * 16 + l15;
        const float* s1 = s0 + (size_t)16 * D_;
        abuf a;
        a.u[0] = pk_bf16(s0[0],            s0[(size_t)D_]);
        a.u[1] = pk_bf16(s0[(size_t)2*D_], s0[(size_t)3*D_]);
        a.u[2] = pk_bf16(s1[0],            s1[(size_t)D_]);
        a.u[3] = pk_bf16(s1[(size_t)2*D_], s1[(size_t)3*D_]);
        *(s16x8*)((char*)s_w + (size_t)slot * 16) = a.v;
    }
}

// ---- K1: stats of y1 = x @ BD(W1); y1 lives only in registers -------------
// Explicit xv0/xv1 double buffer (same structure as k_fused): loads for the
// next tile are issued BEFORE the current tile's compute so they fly under
// the MFMAs. (Single rotating buffer made the compiler serialize: 84 VGPR,
// VALUBusy 3%, 1 TB/s.)
__global__ __launch_bounds__(256, 2) void k_stats1(
    const float* __restrict__ x, const float* __restrict__ W1,
    float* __restrict__ gsum, float* __restrict__ gsq)
{
    __shared__ short s_w[D_ * D_];
    __shared__ float s_sum[D_], s_sq[D_];
    const int tid = threadIdx.x;
    const int p = blockIdx.x / STRIPS, strip = blockIdx.x % STRIPS;
    stage_wp(W1 + (size_t)p * D_ * D_, s_w, tid);
    if (tid < D_) { s_sum[tid] = 0.f; s_sq[tid] = 0.f; }
    __syncthreads();
    const int wave = tid >> 6, lane = tid & 63;
    const int l15 = lane & 15, l4 = lane >> 4;
    const int ldsb = lane * 16;

    f32x4 csum[8], csq[8];
#pragma unroll
    for (int j = 0; j < 8; ++j) { csum[j] = (f32x4){0,0,0,0}; csq[j] = (f32x4){0,0,0,0}; }

    auto LOADX = [&](f32x4 (&xv)[8], int it) {
        const int g = strip * 32 + it * 4 + wave;
        const float* ap = x + (size_t)(g * 16 + l15) * F_ + p * D_ + l4 * 4;
#pragma unroll
        for (int j = 0; j < 8; ++j)
            xv[j] = *(const f32x4*)(ap + j * 16);
    };

    auto TILE = [&](f32x4 (&xv)[8]) {
        abuf a[4];
#pragma unroll
        for (int s = 0; s < 4; ++s) {
            a[s].u[0] = pk_bf16(xv[2*s][0],   xv[2*s][1]);
            a[s].u[1] = pk_bf16(xv[2*s][2],   xv[2*s][3]);
            a[s].u[2] = pk_bf16(xv[2*s+1][0], xv[2*s+1][1]);
            a[s].u[3] = pk_bf16(xv[2*s+1][2], xv[2*s+1][3]);
        }
        f32x4 acc[8];
#pragma unroll
        for (int j = 0; j < 8; ++j) acc[j] = (f32x4){0,0,0,0};
#pragma unroll
        for (int s = 0; s < 4; ++s)
#pragma unroll
            for (int j = 0; j < 8; ++j) {
                s16x8 w = *(const s16x8*)((const char*)s_w + (j * 4 + s) * 1024 + ldsb);
                acc[j] = __builtin_amdgcn_mfma_f32_16x16x32_bf16(w, a[s].v, acc[j], 0, 0, 0);
            }
#pragma unroll
        for (int j = 0; j < 8; ++j)
#pragma unroll
            for (int r = 0; r < 4; ++r) {
                float v = acc[j][r];
                csum[j][r] += v;
                csq[j][r] = fmaf(v, v, csq[j][r]);
            }
    };

    f32x4 xv0[8], xv1[8];
    LOADX(xv0, 0);
#pragma unroll
    for (int h = 0; h < 4; ++h) {
        LOADX(xv1, 2 * h + 1);
        TILE(xv0);
        if (h < 3) LOADX(xv0, 2 * h + 2);
        TILE(xv1);
    }

#pragma unroll
    for (int j = 0; j < 8; ++j)
#pragma unroll
        for (int r = 0; r < 4; ++r) {
            float sm = csum[j][r], q = csq[j][r];
            sm += __shfl_xor(sm, 1); q += __shfl_xor(q, 1);
            sm += __shfl_xor(sm, 2); q += __shfl_xor(q, 2);
            sm += __shfl_xor(sm, 4); q += __shfl_xor(q, 4);
            sm += __shfl_xor(sm, 8); q += __shfl_xor(q, 8);
            if (l15 == 0) {
                atomicAdd(&s_sum[j * 16 + l4 * 4 + r], sm);
                atomicAdd(&s_sq [j * 16 + l4 * 4 + r], q);
            }
        }
    __syncthreads();
    if (tid < D_) {
        atomicAdd(&gsum[p * D_ + tid], s_sum[tid]);
        atomicAdd(&gsq [p * D_ + tid], s_sq[tid]);
    }
}

// ---- K2: y3 = tanh(bn1(x@W1)) @ BD(W2) + x, one x read, fused stats3 ------
// FH: store y3 as fp16 into d_ws (halves the y3 write + next read);
// else f32 into d_out (fallback when ws is too small).
template<bool FH>
__global__ __launch_bounds__(256, 2) void k_fused(
    const float* __restrict__ x, float* __restrict__ yf,
    unsigned short* __restrict__ yh,
    const float* __restrict__ W1, const float* __restrict__ W2,
    const float* __restrict__ sce, const float* __restrict__ she,
    float* __restrict__ gsum, float* __restrict__ gsq)
{
    __shared__ short s_w1[D_ * D_];
    __shared__ short s_w2[D_ * D_];
    __shared__ float s_sc[D_], s_sh[D_];
    __shared__ float s_sum[D_], s_sq[D_];
    const int tid = threadIdx.x;
    const int p = blockIdx.x / STRIPS, strip = blockIdx.x % STRIPS;
    stage_wp(W1 + (size_t)p * D_ * D_, s_w1, tid);
    stage_wp(W2 + (size_t)p * D_ * D_, s_w2, tid);
    if (tid < D_) {
        s_sc[tid] = sce[p * D_ + tid];
        s_sh[tid] = she[p * D_ + tid];
        s_sum[tid] = 0.f; s_sq[tid] = 0.f;
    }
    __syncthreads();
    const int wave = tid >> 6, lane = tid & 63;
    const int l15 = lane & 15, l4 = lane >> 4;
    const int ldsb = lane * 16;

    f32x4 csum[8], csq[8];
#pragma unroll
    for (int j = 0; j < 8; ++j) { csum[j] = (f32x4){0,0,0,0}; csq[j] = (f32x4){0,0,0,0}; }

    auto LOADX = [&](f32x4 (&xv)[8], int it) {
        const int g = strip * 32 + it * 4 + wave;
        const float* ap = x + (size_t)(g * 16 + l15) * F_ + p * D_ + l4 * 4;
#pragma unroll
        for (int j = 0; j < 8; ++j)
            xv[j] = *(const f32x4*)(ap + j * 16);
    };

    auto TILE = [&](f32x4 (&xv)[8], int it) {
        // ---- GEMM1 recompute ----
        abuf a[4];
#pragma unroll
        for (int s = 0; s < 4; ++s) {
            a[s].u[0] = pk_bf16(xv[2*s][0],   xv[2*s][1]);
            a[s].u[1] = pk_bf16(xv[2*s][2],   xv[2*s][3]);
            a[s].u[2] = pk_bf16(xv[2*s+1][0], xv[2*s+1][1]);
            a[s].u[3] = pk_bf16(xv[2*s+1][2], xv[2*s+1][3]);
        }
        f32x4 acc[8];
#pragma unroll
        for (int j = 0; j < 8; ++j) acc[j] = (f32x4){0,0,0,0};
#pragma unroll
        for (int s = 0; s < 4; ++s)
#pragma unroll
            for (int j = 0; j < 8; ++j) {
                s16x8 w = *(const s16x8*)((const char*)s_w1 + (j * 4 + s) * 1024 + ldsb);
                acc[j] = __builtin_amdgcn_mfma_f32_16x16x32_bf16(w, a[s].v, acc[j], 0, 0, 0);
            }
        // ---- bn1 + tanh -> B-fragments for GEMM2 ----
#pragma unroll
        for (int sp = 0; sp < 4; ++sp) {
            const int kb = sp * 32 + l4 * 4;
            f32x4 sc0 = *(const f32x4*)&s_sc[kb], sc1 = *(const f32x4*)&s_sc[kb + 16];
            f32x4 sh0 = *(const f32x4*)&s_sh[kb], sh1 = *(const f32x4*)&s_sh[kb + 16];
            float t0[4], t1[4];
#pragma unroll
            for (int q = 0; q < 4; ++q) {
                t0[q] = tanh_e(fmaf(acc[2*sp][q],   sc0[q], sh0[q]));
                t1[q] = tanh_e(fmaf(acc[2*sp+1][q], sc1[q], sh1[q]));
            }
            a[sp].u[0] = pk_bf16(t0[0], t0[1]);
            a[sp].u[1] = pk_bf16(t0[2], t0[3]);
            a[sp].u[2] = pk_bf16(t1[0], t1[1]);
            a[sp].u[3] = pk_bf16(t1[2], t1[3]);
        }
        // ---- GEMM2 ----
#pragma unroll
        for (int j = 0; j < 8; ++j) acc[j] = (f32x4){0,0,0,0};
#pragma unroll
        for (int sp = 0; sp < 4; ++sp)
#pragma unroll
            for (int j = 0; j < 8; ++j) {
                s16x8 w = *(const s16x8*)((const char*)s_w2 + (j * 4 + sp) * 1024 + ldsb);
                acc[j] = __builtin_amdgcn_mfma_f32_16x16x32_bf16(w, a[sp].v, acc[j], 0, 0, 0);
            }
        // ---- residual from the SAME registers, store, stats ----
        const int g = strip * 32 + it * 4 + wave;
        const size_t rowoff = (size_t)(g * 16 + l15) * F_ + p * D_ + l4 * 4;
#pragma unroll
        for (int j = 0; j < 8; ++j) {
            f32x4 o;
#pragma unroll
            for (int r = 0; r < 4; ++r) {
                float v = acc[j][r] + xv[j][r];
                o[r] = v;
                csum[j][r] += v;
                csq[j][r] = fmaf(v, v, csq[j][r]);
            }
            if (FH) {
                uint32_t h2[2];
                h2[0] = pk_f16(o[0], o[1]);
                h2[1] = pk_f16(o[2], o[3]);
                __builtin_nontemporal_store(*(const uint64_t*)h2,
                                            (uint64_t*)(yh + rowoff + j * 16));
            } else {
                __builtin_nontemporal_store(o, (f32x4*)(yf + rowoff + j * 16));
            }
        }
    };

    f32x4 xv0[8], xv1[8];
    LOADX(xv0, 0);
#pragma unroll
    for (int h = 0; h < 4; ++h) {
        LOADX(xv1, 2 * h + 1);
        TILE(xv0, 2 * h);
        if (h < 3) LOADX(xv0, 2 * h + 2);
        TILE(xv1, 2 * h + 1);
    }

#pragma unroll
    for (int j = 0; j < 8; ++j)
#pragma unroll
        for (int r = 0; r < 4; ++r) {
            float sm = csum[j][r], q = csq[j][r];
            sm += __shfl_xor(sm, 1); q += __shfl_xor(q, 1);
            sm += __shfl_xor(sm, 2); q += __shfl_xor(q, 2);
            sm += __shfl_xor(sm, 4); q += __shfl_xor(q, 4);
            sm += __shfl_xor(sm, 8); q += __shfl_xor(q, 8);
            if (l15 == 0) {
                atomicAdd(&s_sum[j * 16 + l4 * 4 + r], sm);
                atomicAdd(&s_sq [j * 16 + l4 * 4 + r], q);
            }
        }
    __syncthreads();
    if (tid < D_) {
        atomicAdd(&gsum[p * D_ + tid], s_sum[tid]);
        atomicAdd(&gsq [p * D_ + tid], s_sq[tid]);
    }
}

// --- BN finalize: scale/shift pre-multiplied by 2*log2(e) for tanh_e -------
__global__ void k_finalize(const float* __restrict__ sum,
                           const float* __restrict__ sumsq,
                           const float* __restrict__ gamma,
                           const float* __restrict__ beta,
                           float* __restrict__ sce, float* __restrict__ she)
{
    const float L2E2 = 2.f * 1.44269504088896340736f;
    int f = blockIdx.x * blockDim.x + threadIdx.x;
    if (f < F_) {
        float mean = sum[f] * (1.f / B_);
        float var  = sumsq[f] * (1.f / B_) - mean * mean;
        float rstd = rsqrtf(var + 1e-5f);
        float sc = gamma[f] * rstd;
        sce[f] = L2E2 * sc;
        she[f] = L2E2 * (beta[f] - mean * sc);
    }
}

// ----------- final elementwise: o3 = tanh(bn3(y3)) -> d_out (f32) ----------
template<bool FH>
__global__ void k_bn_tanh(const unsigned short* __restrict__ yh,
                          float* __restrict__ out,
                          const float* __restrict__ sce,
                          const float* __restrict__ she)
{
    if (FH) {
        const size_t n8 = (size_t)B_ * F_ / 8;
        size_t i = (size_t)blockIdx.x * blockDim.x + threadIdx.x;
        const size_t stride = (size_t)gridDim.x * blockDim.x;
        for (; i < n8; i += stride) {
            s16x8 hv = *(const s16x8*)(yh + i * 8);
            int col = (int)((i * 8) & (F_ - 1));
            f32x4 sc0 = *(const f32x4*)(sce + col), sc1 = *(const f32x4*)(sce + col + 4);
            f32x4 sh0 = *(const f32x4*)(she + col), sh1 = *(const f32x4*)(she + col + 4);
            f32x4 r0, r1;
#pragma unroll
            for (int t = 0; t < 4; ++t) {
                r0[t] = tanh_e(fmaf(f16_f32((unsigned short)hv[t]),     sc0[t], sh0[t]));
                r1[t] = tanh_e(fmaf(f16_f32((unsigned short)hv[t + 4]), sc1[t], sh1[t]));
            }
            __builtin_nontemporal_store(r0, (f32x4*)(out + i * 8));
            __builtin_nontemporal_store(r1, (f32x4*)(out + i * 8 + 4));
        }
    } else {
        const size_t n4 = (size_t)B_ * F_ / 4;
        size_t i = (size_t)blockIdx.x * blockDim.x + threadIdx.x;
        const size_t stride = (size_t)gridDim.x * blockDim.x;
        for (; i < n4; i += stride) {
            f32x4 v = ((const f32x4*)out)[i];
            int col = (int)((i * 4) & (F_ - 1));
            f32x4 sc = *(const f32x4*)(sce + col);
            f32x4 sh = *(const f32x4*)(she + col);
            f32x4 r;
#pragma unroll
            for (int t = 0; t < 4; ++t) r[t] = tanh_e(fmaf(v[t], sc[t], sh[t]));
            __builtin_nontemporal_store(r, (f32x4*)out + i);
        }
    }
}

extern "C" void kernel_launch(void* const* d_in, const int* in_sizes, int n_in,
                              void* d_out, int out_size, void* d_ws, size_t ws_size,
                              hipStream_t stream) {
    const float* x      = (const float*)d_in[0];
    const float* W1     = (const float*)d_in[1];
    // d_in[2] = bias1 (cancels inside BN1)
    const float* W2     = (const float*)d_in[3];
    // d_in[4] = bias2 (cancels inside BN3)
    const float* gamma1 = (const float*)d_in[5];
    const float* beta1  = (const float*)d_in[6];
    const float* gamma3 = (const float*)d_in[7];
    const float* beta3  = (const float*)d_in[8];

    float* yf = (float*)d_out;
    float* S  = (float*)d_ws;                  // 128KB stats block
    float* sum1 = S;                           // zeroed
    float* sq1  = S + 4096;                    // zeroed
    float* sum3 = S + 8192;                    // zeroed
    float* sq3  = S + 12288;                   // zeroed
    float* sce1 = S + 16384;
    float* she1 = S + 20480;
    float* sce3 = S + 24576;
    float* she3 = S + 28672;
    unsigned short* yh = (unsigned short*)((char*)d_ws + 128 * 1024);

    const bool fh = ws_size >= (size_t)128 * 1024 + (size_t)B_ * F_ * 2;

    hipMemsetAsync(d_ws, 0, 4 * 4096 * sizeof(float), stream);

    k_stats1<<<P_ * STRIPS, 256, 0, stream>>>(x, W1, sum1, sq1);
    k_finalize<<<F_ / 256, 256, 0, stream>>>(sum1, sq1, gamma1, beta1, sce1, she1);
    if (fh) {
        k_fused<true><<<P_ * STRIPS, 256, 0, stream>>>(x, yf, yh, W1, W2, sce1, she1, sum3, sq3);
        k_finalize<<<F_ / 256, 256, 0, stream>>>(sum3, sq3, gamma3, beta3, sce3, she3);
        k_bn_tanh<true><<<4096, 256, 0, stream>>>(yh, yf, sce3, she3);
    } else {
        k_fused<false><<<P_ * STRIPS, 256, 0, stream>>>(x, yf, yh, W1, W2, sce1, she1, sum3, sq3);
        k_finalize<<<F_ / 256, 256, 0, stream>>>(sum3, sq3, gamma3, beta3, sce3, she3);
        k_bn_tanh<false><<<4096, 256, 0, stream>>>((const unsigned short*)yf, yf, sce3, she3);
    }
}